// Round 8
// baseline (359.358 us; speedup 1.0000x reference)
//
#include <hip/hip_runtime.h>

// ---------------------------------------------------------------------------
// VectorQuantizerEMA — round 12: x direct global->reg, e-only LDS staging
//   * argmin back to r10 skeleton (4 waves, 512 blocks, drain barrier/chunk)
//   * x fragments loaded straight from the frag-order global planes into
//     registers (coalesced dwordx4) — halves LDS reads, cuts staged bytes
//     per barrier 48KB->16KB, LDS 69.6KB->36.9KB (3-4 blocks/CU possible)
//   * e planes double-buffered in LDS as before (all 4 waves stage, 4 each)
//   * fold / top-3 merge / tiered rescue byte-identical to round 10 (passed)
// ---------------------------------------------------------------------------

#define DECAY 0.99f
#define OMD   0.01f
#define EPSC  1e-5f
#define MARGIN 0.025f

constexpr int Dq = 256;
constexpr int Kn = 2048;
constexpr int Nq = 32768;
constexpr int MAXITEMS = 3072;   // sum ceil(cnt/32) <= 2048 + 32768/32

typedef short bf16x8 __attribute__((ext_vector_type(8)));
typedef float f32x4 __attribute__((ext_vector_type(4)));

__device__ __forceinline__ unsigned short f2bf_rne(float f) {
    unsigned int u = __float_as_uint(f);
    unsigned int r = u + 0x7FFFu + ((u >> 16) & 1u);
    return (unsigned short)(r >> 16);
}
__device__ __forceinline__ float bf2f(unsigned short h) {
    return __uint_as_float(((unsigned int)h) << 16);
}
__device__ __forceinline__ void async_copy16(const void* g, void* l) {
    __builtin_amdgcn_global_load_lds(
        (const __attribute__((address_space(1))) unsigned int*)g,
        (__attribute__((address_space(3))) unsigned int*)l, 16, 0, 0);
}
__device__ __forceinline__ uint4 packbf(const unsigned short* h) {
    uint4 u;
    u.x = (unsigned)h[0] | ((unsigned)h[1] << 16);
    u.y = (unsigned)h[2] | ((unsigned)h[3] << 16);
    u.z = (unsigned)h[4] | ((unsigned)h[5] << 16);
    u.w = (unsigned)h[6] | ((unsigned)h[7] << 16);
    return u;
}

// ---------------- convert: fp32 -> frag-order bf16 hi/lo planes + enorm -----
__global__ __launch_bounds__(256) void convert_kernel(
    const float* __restrict__ x, const float* __restrict__ emb,
    unsigned char* __restrict__ xh_g, unsigned char* __restrict__ xl_g,
    unsigned char* __restrict__ eh_g, unsigned char* __restrict__ el_g,
    float* __restrict__ enorm, int* __restrict__ counts,
    float* __restrict__ loss_acc, int* __restrict__ nflagF,
    int* __restrict__ nitems, int* __restrict__ nflagP)
{
    __shared__ float part[32][8];
    int b = blockIdx.x;
    bool is_e = (b >= 1024);
    const float* src = is_e ? emb : x;
    unsigned char* hg = is_e ? eh_g : xh_g;
    unsigned char* lg = is_e ? el_g : xl_g;
    int base_row = (is_e ? (b - 1024) : b) * 32;
    int t = threadIdx.x;
    if (b == 1024) {
        for (int i = t; i < Kn; i += 256) counts[i] = 0;
        if (t == 0) { loss_acc[0] = 0.f; nflagF[0] = 0; nitems[0] = 0; nflagP[0] = 0; }
    }
    int rg = t >> 7, ds = (t >> 4) & 7, rl = t & 15;
    int r = base_row + rg * 16 + rl;
    const float4* s4 = (const float4*)(src + (size_t)r * Dq + ds * 32);
    float v[32];
#pragma unroll
    for (int i = 0; i < 8; ++i) {
        float4 f = s4[i];
        v[i * 4 + 0] = f.x; v[i * 4 + 1] = f.y; v[i * 4 + 2] = f.z; v[i * 4 + 3] = f.w;
    }
    unsigned short hh[32], ll[32];
#pragma unroll
    for (int i = 0; i < 32; ++i) {
        hh[i] = f2bf_rne(v[i]);
        ll[i] = f2bf_rne(v[i] - bf2f(hh[i]));
    }
    size_t gb = ((size_t)(r >> 4) * 8 + ds) * 1024 + rl * 16;
#pragma unroll
    for (int qd = 0; qd < 4; ++qd) {
        *(uint4*)(hg + gb + qd * 256) = packbf(hh + qd * 8);
        *(uint4*)(lg + gb + qd * 256) = packbf(ll + qd * 8);
    }
    if (is_e) {
        float ps = 0.f;
#pragma unroll
        for (int i = 0; i < 32; ++i) ps += v[i] * v[i];
        part[rg * 16 + rl][ds] = ps;
        __syncthreads();
        if (t < 32) {
            float s = 0.f;
#pragma unroll
            for (int j = 0; j < 8; ++j) s += part[t][j];
            enorm[base_row + t] = s;
        }
    }
}

// ---------------- argmin: 128q x 1024k, x->regs direct, e dbuf in LDS -------
// LDS map: ebuf[2] 16KB each (eh 8 blk @+0, el 8 blk @+8192); enorm @32768.
__global__ __launch_bounds__(256, 2) void argmin_kernel(
    const unsigned char* __restrict__ xh_g, const unsigned char* __restrict__ xl_g,
    const unsigned char* __restrict__ eh_g, const unsigned char* __restrict__ el_g,
    const float* __restrict__ enorm,
    float* __restrict__ ws_s1, float* __restrict__ ws_s2,
    float* __restrict__ ws_s3, int* __restrict__ ws_ik)
{
    __shared__ __align__(16) unsigned char lds[36864];
    const int tid = threadIdx.x;
    const int lane = tid & 63, wave = tid >> 6;
    const int wq = wave >> 1, wk = wave & 1;
    const int rl = lane & 15, quad = lane >> 4;
    const int b = blockIdx.x;
    const int qb = (b & 7) * 32 + ((b >> 3) >> 1);   // bijective over 512
    const int split = (b >> 3) & 1;
    const int lane16 = lane * 16;

    // stage e chunk s into ebuf[s&1]: all 4 waves, 4 blocks each
    auto STAGE = [&](int s) {
        const int kt = s >> 3, ch = s & 7;
        unsigned char* buf = lds + (s & 1) * 16384 + ((wave < 2) ? 0 : 8192);
        const unsigned char* src = (wave < 2) ? eh_g : el_g;
        const int jj0 = (wave & 1) * 4;
#pragma unroll
        for (int jj = 0; jj < 4; ++jj)
            async_copy16(src + ((size_t)(split * 64 + kt * 8 + jj0 + jj) * 8 + ch) * 1024
                             + lane16,
                         buf + (jj0 + jj) * 1024);
    };

    ((float4*)(lds + 32768))[tid] = ((const float4*)(enorm + split * 1024))[tid];
    STAGE(0);
    __syncthreads();

    float s1[16], s2[16], s3[16];
    int i1[16], i2[16];
#pragma unroll
    for (int s = 0; s < 16; ++s) {
        s1[s] = 3.4e38f; s2[s] = 3.4e38f; s3[s] = 3.4e38f; i1[s] = 0; i2[s] = 0;
    }
    f32x4 acc[4][4];

    for (int s = 0; s < 64; ++s) {
        const int kt = s >> 3, ch = s & 7;
        if (ch == 0) {
#pragma unroll
            for (int mf = 0; mf < 4; ++mf)
#pragma unroll
                for (int nf = 0; nf < 4; ++nf)
                    acc[mf][nf] = (f32x4){0.f, 0.f, 0.f, 0.f};
        }
        if (s < 63) STAGE(s + 1);          // e prefetch in flight across compute

        // x fragments: direct global->reg (frag-order planes, coalesced 16B)
        bf16x8 ah[4], al[4], bh[4], bl[4];
#pragma unroll
        for (int mf = 0; mf < 4; ++mf) {
            size_t goff = ((size_t)(qb * 8 + wq * 4 + mf) * 8 + ch) * 1024 + lane16;
            ah[mf] = *(const bf16x8*)(xh_g + goff);
            al[mf] = *(const bf16x8*)(xl_g + goff);
        }
        const unsigned char* eb = lds + (s & 1) * 16384;
#pragma unroll
        for (int nf = 0; nf < 4; ++nf) {
            bh[nf] = *(const bf16x8*)(eb + (wk * 4 + nf) * 1024 + lane16);
            bl[nf] = *(const bf16x8*)(eb + 8192 + (wk * 4 + nf) * 1024 + lane16);
        }
#pragma unroll
        for (int mf = 0; mf < 4; ++mf)
#pragma unroll
            for (int nf = 0; nf < 4; ++nf) {
                acc[mf][nf] = __builtin_amdgcn_mfma_f32_16x16x32_bf16(
                    ah[mf], bh[nf], acc[mf][nf], 0, 0, 0);
                acc[mf][nf] = __builtin_amdgcn_mfma_f32_16x16x32_bf16(
                    ah[mf], bl[nf], acc[mf][nf], 0, 0, 0);
                acc[mf][nf] = __builtin_amdgcn_mfma_f32_16x16x32_bf16(
                    al[mf], bh[nf], acc[mf][nf], 0, 0, 0);
            }

        if (ch == 7) {
            // fold scores; codes arrive in ascending order per slot
#pragma unroll
            for (int nf = 0; nf < 4; ++nf) {
                float ee = *(const float*)(lds + 32768 +
                             (kt * 128 + wk * 64 + nf * 16 + rl) * 4);
                int code = kt * 4 + nf;
#pragma unroll
                for (int mf = 0; mf < 4; ++mf)
#pragma unroll
                    for (int r = 0; r < 4; ++r) {
                        int slot = mf * 4 + r;
                        float sc = fmaf(-2.f, acc[mf][nf][r], ee);
                        bool lt1 = sc < s1[slot];
                        bool lt2 = sc < s2[slot];
                        s3[slot] = lt2 ? s2[slot] : fminf(s3[slot], sc);
                        s2[slot] = lt1 ? s1[slot] : (lt2 ? sc : s2[slot]);
                        i2[slot] = lt1 ? i1[slot] : (lt2 ? code : i2[slot]);
                        s1[slot] = lt1 ? sc : s1[slot];
                        i1[slot] = lt1 ? code : i1[slot];
                    }
            }
        }
        __syncthreads();   // drains STAGE(s+1) (16KB) after the 48-MFMA cluster
    }

    // local codes -> global code ids
    int k1[16], k2[16];
#pragma unroll
    for (int s = 0; s < 16; ++s) {
        k1[s] = split * 1024 + (i1[s] >> 2) * 128 + wk * 64 + (i1[s] & 3) * 16 + rl;
        k2[s] = split * 1024 + (i2[s] >> 2) * 128 + wk * 64 + (i2[s] & 3) * 16 + rl;
    }
    // butterfly merge across the 16 lanes holding the same query rows
#pragma unroll
    for (int m = 1; m <= 8; m <<= 1) {
#pragma unroll
        for (int s = 0; s < 16; ++s) {
            float t1 = __shfl_xor(s1[s], m, 64);
            float t2 = __shfl_xor(s2[s], m, 64);
            float t3 = __shfl_xor(s3[s], m, 64);
            int   j1 = __shfl_xor(k1[s], m, 64);
            int   j2 = __shfl_xor(k2[s], m, 64);
            bool a1 = (t1 < s1[s]) || (t1 == s1[s] && j1 < k1[s]);
            bool a2 = (t1 < s2[s]) || (t1 == s2[s] && j1 < k2[s]);
            s3[s] = a2 ? s2[s] : fminf(s3[s], t1);
            s2[s] = a1 ? s1[s] : (a2 ? t1 : s2[s]);
            k2[s] = a1 ? k1[s] : (a2 ? j1 : k2[s]);
            s1[s] = a1 ? t1 : s1[s];
            k1[s] = a1 ? j1 : k1[s];
            bool b1 = (t2 < s1[s]) || (t2 == s1[s] && j2 < k1[s]);
            bool b2 = (t2 < s2[s]) || (t2 == s2[s] && j2 < k2[s]);
            s3[s] = b2 ? s2[s] : fminf(s3[s], t2);
            s2[s] = b1 ? s1[s] : (b2 ? t2 : s2[s]);
            k2[s] = b1 ? k1[s] : (b2 ? j2 : k2[s]);
            s1[s] = b1 ? t2 : s1[s];
            k1[s] = b1 ? j2 : k1[s];
            s3[s] = fminf(s3[s], t3);
        }
    }
    __syncthreads();
    float* rs1 = (float*)lds;
    float* rs2 = (float*)(lds + 1024);
    float* rs3 = (float*)(lds + 2048);
    int*   rk  = (int*)(lds + 3072);
    if (rl == 0) {
#pragma unroll
        for (int s = 0; s < 16; ++s) {
            int ql = wq * 64 + (s >> 2) * 16 + quad * 4 + (s & 3);
            rs1[ql * 2 + wk] = s1[s];
            rs2[ql * 2 + wk] = s2[s];
            rs3[ql * 2 + wk] = s3[s];
            rk[ql * 2 + wk]  = k1[s] | (k2[s] << 11);
        }
    }
    __syncthreads();
    if (tid < 128) {
        float a1 = rs1[tid * 2], a2 = rs2[tid * 2], a3 = rs3[tid * 2];
        int kk = rk[tid * 2];
        int m1 = kk & 2047, m2 = (kk >> 11) & 2047;
        float t1 = rs1[tid * 2 + 1], t2 = rs2[tid * 2 + 1], t3 = rs3[tid * 2 + 1];
        int kj = rk[tid * 2 + 1];
        int j1 = kj & 2047, j2 = (kj >> 11) & 2047;
        bool c1 = (t1 < a1) || (t1 == a1 && j1 < m1);
        bool c2 = (t1 < a2) || (t1 == a2 && j1 < m2);
        a3 = c2 ? a2 : fminf(a3, t1);
        a2 = c1 ? a1 : (c2 ? t1 : a2);
        m2 = c1 ? m1 : (c2 ? j1 : m2);
        a1 = c1 ? t1 : a1;
        m1 = c1 ? j1 : m1;
        bool d1 = (t2 < a1) || (t2 == a1 && j2 < m1);
        bool d2 = (t2 < a2) || (t2 == a2 && j2 < m2);
        a3 = d2 ? a2 : fminf(a3, t2);
        a2 = d1 ? a1 : (d2 ? t2 : a2);
        m2 = d1 ? m1 : (d2 ? j2 : m2);
        a1 = d1 ? t2 : a1;
        m1 = d1 ? j2 : m1;
        a3 = fminf(a3, t3);
        int q = qb * 128 + tid;
        ws_s1[split * Nq + q] = a1;
        ws_s2[split * Nq + q] = a2;
        ws_s3[split * Nq + q] = a3;
        ws_ik[split * Nq + q] = m1 | (m2 << 11);
    }
}

// ---------------- pick: merge 2 splits, route to pair/full rescue -----------
__global__ __launch_bounds__(256) void pick_kernel(
    const float* __restrict__ ws_s1, const float* __restrict__ ws_s2,
    const float* __restrict__ ws_s3, const int* __restrict__ ws_ik,
    int* __restrict__ idx,
    int* __restrict__ nflagF, int* __restrict__ flaglist,
    int* __restrict__ nflagP, int* __restrict__ pairlist)
{
    int q = blockIdx.x * 256 + threadIdx.x;
    float a1 = ws_s1[q], a2 = ws_s2[q], a3 = ws_s3[q];
    int kk = ws_ik[q];
    int m1 = kk & 2047, m2 = (kk >> 11) & 2047;
    float t1 = ws_s1[Nq + q], t2 = ws_s2[Nq + q], t3 = ws_s3[Nq + q];
    int kj = ws_ik[Nq + q];
    int j1 = kj & 2047, j2 = (kj >> 11) & 2047;
    bool c1 = (t1 < a1) || (t1 == a1 && j1 < m1);
    bool c2 = (t1 < a2) || (t1 == a2 && j1 < m2);
    a3 = c2 ? a2 : fminf(a3, t1);
    a2 = c1 ? a1 : (c2 ? t1 : a2);
    m2 = c1 ? m1 : (c2 ? j1 : m2);
    a1 = c1 ? t1 : a1;
    m1 = c1 ? j1 : m1;
    bool d1 = (t2 < a1) || (t2 == a1 && j2 < m1);
    bool d2 = (t2 < a2) || (t2 == a2 && j2 < m2);
    a3 = d2 ? a2 : fminf(a3, t2);
    a2 = d1 ? a1 : (d2 ? t2 : a2);
    m2 = d1 ? m1 : (d2 ? j2 : m2);
    a1 = d1 ? t2 : a1;
    m1 = d1 ? j2 : m1;
    a3 = fminf(a3, t3);

    idx[q] = m1;
    if (a3 - a1 < MARGIN) {
        int p = atomicAdd(nflagF, 1);
        flaglist[p] = q;
    } else if (a2 - a1 < MARGIN) {
        int p = atomicAdd(nflagP, 1);
        pairlist[p] = q | (m2 << 16);
    }
}

// ---------------- rescue_full: exact fp32 full scan -------------------------
__global__ __launch_bounds__(256) void rescue_kernel(
    const float* __restrict__ x, const float* __restrict__ emb,
    const float* __restrict__ enorm, const int* __restrict__ flaglist,
    const int* __restrict__ nflag, int* __restrict__ idx)
{
    __shared__ float xs[256];
    __shared__ float bsc[256];
    __shared__ int bix[256];
    int nf = nflag[0];
    int t = threadIdx.x;
    for (int it = blockIdx.x; it < nf; it += gridDim.x) {
        __syncthreads();
        int q = flaglist[it];
        xs[t] = x[(size_t)q * Dq + t];
        __syncthreads();
        float best = 3.4e38f;
        int bk = 0;
        for (int j = 0; j < 8; ++j) {
            int k = j * 256 + t;
            const float4* e4 = (const float4*)(emb + (size_t)k * Dq);
            const float4* x4 = (const float4*)xs;
            float d = 0.f;
#pragma unroll 8
            for (int c = 0; c < 64; ++c) {
                float4 e = e4[c], xv = x4[c];
                d = fmaf(e.x, xv.x, d); d = fmaf(e.y, xv.y, d);
                d = fmaf(e.z, xv.z, d); d = fmaf(e.w, xv.w, d);
            }
            float sc = enorm[k] - 2.f * d;
            if (sc < best || (sc == best && k < bk)) { best = sc; bk = k; }
        }
        bsc[t] = best; bix[t] = bk;
        __syncthreads();
        for (int o = 128; o > 0; o >>= 1) {
            if (t < o) {
                float so = bsc[t + o]; int io = bix[t + o];
                if (so < bsc[t] || (so == bsc[t] && io < bix[t])) {
                    bsc[t] = so; bix[t] = io;
                }
            }
            __syncthreads();
        }
        if (t == 0) idx[q] = bix[0];
    }
}

// ---------------- rescue_pair: exact fp32 for {i1,i2}, 1 thread/query -------
__global__ __launch_bounds__(256) void rescue_pair_kernel(
    const float* __restrict__ x, const float* __restrict__ emb,
    const float* __restrict__ enorm, const int* __restrict__ pairlist,
    const int* __restrict__ nflagP, int* __restrict__ idx)
{
    int np = nflagP[0];
    for (int p = blockIdx.x * 256 + threadIdx.x; p < np; p += gridDim.x * 256) {
        int e = pairlist[p];
        int q = e & 0xFFFF;
        int c2 = e >> 16;
        int c1 = idx[q];
        const float4* x4 = (const float4*)(x + (size_t)q * Dq);
        const float4* e1 = (const float4*)(emb + (size_t)c1 * Dq);
        const float4* e2 = (const float4*)(emb + (size_t)c2 * Dq);
        float d1 = 0.f, d2 = 0.f;
#pragma unroll 8
        for (int c = 0; c < 64; ++c) {
            float4 xv = x4[c];
            float4 ea = e1[c];
            float4 eb = e2[c];
            d1 = fmaf(ea.x, xv.x, d1); d1 = fmaf(ea.y, xv.y, d1);
            d1 = fmaf(ea.z, xv.z, d1); d1 = fmaf(ea.w, xv.w, d1);
            d2 = fmaf(eb.x, xv.x, d2); d2 = fmaf(eb.y, xv.y, d2);
            d2 = fmaf(eb.z, xv.z, d2); d2 = fmaf(eb.w, xv.w, d2);
        }
        float sc1 = enorm[c1] - 2.f * d1;
        float sc2 = enorm[c2] - 2.f * d2;
        if (sc2 < sc1 || (sc2 == sc1 && c2 < c1)) idx[q] = c2;
    }
}

// ---------------- hist: histogram of final indices --------------------------
__global__ __launch_bounds__(256) void hist_kernel(const int* __restrict__ idx,
                                                   int* __restrict__ counts) {
    int q = blockIdx.x * 256 + threadIdx.x;
    atomicAdd(&counts[idx[q]], 1);
}

// ---------------- scan: offsets + smoothed counts + work items --------------
__global__ __launch_bounds__(256) void scan_kernel(
    const int* __restrict__ counts, const float* __restrict__ ema_count,
    int* __restrict__ offs, int* __restrict__ cursor,
    float* __restrict__ cnew, float* __restrict__ out_count,
    int* __restrict__ items, int* __restrict__ nitems)
{
    __shared__ int   si[256];
    __shared__ float sf[256];
    int t = threadIdx.x;
    int c[8], pre[8];
    int run = 0;
    float se = 0.f;
#pragma unroll
    for (int i = 0; i < 8; ++i) {
        c[i] = counts[t * 8 + i];
        pre[i] = run;
        run += c[i];
        se += ema_count[t * 8 + i];
    }
    si[t] = run;
    sf[t] = se;
    __syncthreads();
    for (int off = 1; off < 256; off <<= 1) {
        int v = (t >= off) ? si[t - off] : 0;
        __syncthreads();
        si[t] += v;
        __syncthreads();
    }
    int total_n = si[255];
    int base = si[t] - run;
    for (int off = 128; off > 0; off >>= 1) {
        if (t < off) sf[t] += sf[t + off];
        __syncthreads();
    }
    float total = DECAY * sf[0] + OMD * (float)total_n;
    float denom = total + 2048.0f * EPSC;
#pragma unroll
    for (int i = 0; i < 8; ++i) {
        int k = t * 8 + i;
        int o = base + pre[i];
        offs[k] = o;
        cursor[k] = o;
        float ck = DECAY * ema_count[k] + OMD * (float)c[i];
        float v = (ck + EPSC) / denom * total;
        cnew[k] = v;
        out_count[k] = v;
        if (c[i] > 0) {
            int nit = (c[i] + 31) >> 5;
            int ib = atomicAdd(nitems, nit);
            for (int j = 0; j < nit; ++j)
                items[ib + j] = (k << 17) | (o + j * 32);
        }
    }
}

// ---------------- fill: bucket queries by code ------------------------------
__global__ __launch_bounds__(256) void fill_kernel(const int* __restrict__ idx,
                                                   int* __restrict__ cursor,
                                                   int* __restrict__ sorted) {
    int n = blockIdx.x * 256 + threadIdx.x;
    int v = idx[n];
    int pos = atomicAdd(&cursor[v], 1);
    sorted[pos] = n;
}

// ---------------- weight_partial: <=32 rows per item, atomic accum ----------
__global__ __launch_bounds__(256) void weight_partial_kernel(
    const float* __restrict__ x, const int* __restrict__ sorted,
    const int* __restrict__ items, const int* __restrict__ nitems,
    const int* __restrict__ counts, const int* __restrict__ offs,
    float* __restrict__ accum)
{
    if ((int)blockIdx.x >= nitems[0]) return;
    int it = items[blockIdx.x];
    int k = it >> 17;
    int start = it & 0x1FFFF;
    int end = min(start + 32, offs[k] + counts[k]);
    int t = threadIdx.x;
    float acc = 0.f;
    int j = start;
    for (; j + 4 <= end; j += 4) {
        int n0 = sorted[j + 0], n1 = sorted[j + 1];
        int n2 = sorted[j + 2], n3 = sorted[j + 3];
        float v0 = x[(size_t)n0 * Dq + t];
        float v1 = x[(size_t)n1 * Dq + t];
        float v2 = x[(size_t)n2 * Dq + t];
        float v3 = x[(size_t)n3 * Dq + t];
        acc += v0 + v1 + v2 + v3;
    }
    for (; j < end; ++j) {
        int n = sorted[j];
        acc += x[(size_t)n * Dq + t];
    }
    atomicAdd(&accum[(size_t)k * Dq + t], acc);
}

// ---------------- weight_final: EMA + divide --------------------------------
__global__ __launch_bounds__(256) void weight_final_kernel(
    const float* __restrict__ accum, const float* __restrict__ ema_weight,
    const float* __restrict__ cnew,
    float* __restrict__ out_embed, float* __restrict__ out_weight)
{
    int gi = blockIdx.x * 256 + threadIdx.x;   // float4 index
    int k = gi >> 6;                           // 64 float4 per row
    float4 a = ((const float4*)accum)[gi];
    float4 ew = ((const float4*)ema_weight)[gi];
    float inv = 1.f / cnew[k];
    float4 w;
    w.x = DECAY * ew.x + OMD * a.x;
    w.y = DECAY * ew.y + OMD * a.y;
    w.z = DECAY * ew.z + OMD * a.z;
    w.w = DECAY * ew.w + OMD * a.w;
    ((float4*)out_weight)[gi] = w;
    float4 e;
    e.x = w.x * inv; e.y = w.y * inv; e.z = w.z * inv; e.w = w.w * inv;
    ((float4*)out_embed)[gi] = e;
}

// ---------------- finalize: idx_f + gather z_q + loss -----------------------
__global__ __launch_bounds__(256) void finalize_kernel(
    const int* __restrict__ idx, const float* __restrict__ x,
    const float* __restrict__ emb, float* __restrict__ idx_f_out,
    float* __restrict__ zq_out, float* __restrict__ loss_acc)
{
    __shared__ int sidx[64];
    __shared__ float lpart[4];
    const int tid = threadIdx.x;
    const int q0 = blockIdx.x * 64;
    if (tid < 64) {
        int b = idx[q0 + tid];
        idx_f_out[q0 + tid] = (float)b;
        sidx[tid] = b;
    }
    __syncthreads();
    int gq = tid >> 2, part = tid & 3;
    int bk = sidx[gq];
    const float4* ev = (const float4*)&emb[(size_t)bk * Dq + part * 64];
    const float4* xv = (const float4*)&x[(size_t)(q0 + gq) * Dq + part * 64];
    float4* ov = (float4*)&zq_out[(size_t)(q0 + gq) * Dq + part * 64];
    float lacc = 0.f;
#pragma unroll 4
    for (int t2 = 0; t2 < 16; ++t2) {
        float4 e4 = ev[t2];
        float4 x4 = xv[t2];
        ov[t2] = e4;
        float d0 = x4.x - e4.x, d1 = x4.y - e4.y;
        float d2 = x4.z - e4.z, d3 = x4.w - e4.w;
        lacc += d0 * d0 + d1 * d1 + d2 * d2 + d3 * d3;
    }
#pragma unroll
    for (int o = 32; o > 0; o >>= 1) lacc += __shfl_down(lacc, o, 64);
    if ((tid & 63) == 0) lpart[tid >> 6] = lacc;
    __syncthreads();
    if (tid == 0)
        atomicAdd(loss_acc, lpart[0] + lpart[1] + lpart[2] + lpart[3]);
}

// ---------------- loss_final ------------------------------------------------
__global__ void loss_final_kernel(const float* __restrict__ loss_acc,
                                  float* __restrict__ out_cb,
                                  float* __restrict__ out_cm) {
    float v = loss_acc[0] / (float)((size_t)Nq * Dq);
    out_cb[0] = v;
    out_cm[0] = v;
}

// ---------------------------------------------------------------------------
extern "C" void kernel_launch(void* const* d_in, const int* in_sizes, int n_in,
                              void* d_out, int out_size, void* d_ws, size_t ws_size,
                              hipStream_t stream) {
    const float* z_e        = (const float*)d_in[0];
    const float* emb        = (const float*)d_in[1];
    const float* ema_count  = (const float*)d_in[2];
    const float* ema_weight = (const float*)d_in[3];

    float* out_zq     = (float*)d_out;
    float* out_idx    = out_zq + (size_t)Nq * Dq;            // 8388608
    float* out_cb     = out_idx + Nq;
    float* out_cm     = out_cb + 1;
    float* out_embed  = out_cm + 1;                           // 8421378
    float* out_count  = out_embed + (size_t)Kn * Dq;
    float* out_weight = out_count + Kn;

    // scratch planes + accum live in d_out regions written later:
    unsigned char* xh_g = (unsigned char*)d_out;              // 16 MB (z_q area)
    unsigned char* xl_g = xh_g + 16777216;                    // 16 MB
    size_t eh_off = (((size_t)8421378 * 4) + 15) & ~(size_t)15;
    unsigned char* eh_g = (unsigned char*)d_out + eh_off;     // 1 MB (embed area)
    unsigned char* el_g = eh_g + 1048576;                     // 1 MB
    float* accum = (float*)d_out;                             // 2 MB, zeroed post-argmin

    char* ws = (char*)d_ws;
    float* enorm    = (float*)(ws + 0);
    int*   counts   = (int*)(ws + 8192);
    int*   offs     = (int*)(ws + 16384);
    int*   cursor   = (int*)(ws + 24576);
    float* cnew     = (float*)(ws + 32768);
    float* loss_acc = (float*)(ws + 40960);
    int*   nflagF   = (int*)(ws + 40964);
    int*   nitems   = (int*)(ws + 40968);
    int*   nflagP   = (int*)(ws + 40972);
    int*   idx      = (int*)(ws + 49152);       // 32768 i
    int*   sorted   = (int*)(ws + 180224);      // 32768 i
    int*   flaglist = (int*)(ws + 311296);      // 32768 i
    float* ws_s1    = (float*)(ws + 442368);    // 2*32768 f
    float* ws_s2    = (float*)(ws + 704512);    // 2*32768 f
    float* ws_s3    = (float*)(ws + 966656);    // 2*32768 f
    int*   ws_ik    = (int*)(ws + 1228800);     // 2*32768 i
    int*   pairlist = (int*)(ws + 1490944);     // 32768 i
    int*   items    = (int*)(ws + 1622016);     // 3072 i

    convert_kernel<<<1088, 256, 0, stream>>>(z_e, emb, xh_g, xl_g, eh_g, el_g,
                                             enorm, counts, loss_acc, nflagF,
                                             nitems, nflagP);
    argmin_kernel<<<512, 256, 0, stream>>>(xh_g, xl_g, eh_g, el_g, enorm,
                                           ws_s1, ws_s2, ws_s3, ws_ik);
    hipMemsetAsync(accum, 0, (size_t)Kn * Dq * sizeof(float), stream);
    pick_kernel<<<Nq / 256, 256, 0, stream>>>(ws_s1, ws_s2, ws_s3, ws_ik, idx,
                                              nflagF, flaglist, nflagP, pairlist);
    rescue_kernel<<<1024, 256, 0, stream>>>(z_e, emb, enorm, flaglist, nflagF, idx);
    rescue_pair_kernel<<<128, 256, 0, stream>>>(z_e, emb, enorm, pairlist,
                                                nflagP, idx);
    hist_kernel<<<Nq / 256, 256, 0, stream>>>(idx, counts);
    scan_kernel<<<1, 256, 0, stream>>>(counts, ema_count, offs, cursor, cnew,
                                       out_count, items, nitems);
    fill_kernel<<<Nq / 256, 256, 0, stream>>>(idx, cursor, sorted);
    weight_partial_kernel<<<MAXITEMS, 256, 0, stream>>>(z_e, sorted, items, nitems,
                                                        counts, offs, accum);
    weight_final_kernel<<<Kn * Dq / 1024, 256, 0, stream>>>(accum, ema_weight, cnew,
                                                            out_embed, out_weight);
    finalize_kernel<<<Nq / 64, 256, 0, stream>>>(idx, z_e, emb, out_idx,
                                                 out_zq, loss_acc);
    loss_final_kernel<<<1, 1, 0, stream>>>(loss_acc, out_cb, out_cm);
}

// Round 9
// 320.034 us; speedup vs baseline: 1.1229x; 1.1229x over previous
//
#include <hip/hip_runtime.h>

// ---------------------------------------------------------------------------
// VectorQuantizerEMA — round 13: r10 argmin (verified 131us) + fused tail
//   * argmin byte-identical to round 10 (322us total, best verified)
//   * pick absorbs hist (counts m1; rescues fix up on idx change) and the
//     accum memset (blocks >=128 zero 2MB)
//   * rescue_full + rescue_pair merged into one dispatch (disjoint queries)
//   * weight_final + finalize merged into one 1024-block dispatch
//   * 13 -> 9 dispatches; all arithmetic byte-identical to round 10
// ---------------------------------------------------------------------------

#define DECAY 0.99f
#define OMD   0.01f
#define EPSC  1e-5f
#define MARGIN 0.025f

constexpr int Dq = 256;
constexpr int Kn = 2048;
constexpr int Nq = 32768;
constexpr int MAXITEMS = 3072;   // sum ceil(cnt/32) <= 2048 + 32768/32

typedef short bf16x8 __attribute__((ext_vector_type(8)));
typedef float f32x4 __attribute__((ext_vector_type(4)));

__device__ __forceinline__ unsigned short f2bf_rne(float f) {
    unsigned int u = __float_as_uint(f);
    unsigned int r = u + 0x7FFFu + ((u >> 16) & 1u);
    return (unsigned short)(r >> 16);
}
__device__ __forceinline__ float bf2f(unsigned short h) {
    return __uint_as_float(((unsigned int)h) << 16);
}
__device__ __forceinline__ void async_copy16(const void* g, void* l) {
    __builtin_amdgcn_global_load_lds(
        (const __attribute__((address_space(1))) unsigned int*)g,
        (__attribute__((address_space(3))) unsigned int*)l, 16, 0, 0);
}
__device__ __forceinline__ uint4 packbf(const unsigned short* h) {
    uint4 u;
    u.x = (unsigned)h[0] | ((unsigned)h[1] << 16);
    u.y = (unsigned)h[2] | ((unsigned)h[3] << 16);
    u.z = (unsigned)h[4] | ((unsigned)h[5] << 16);
    u.w = (unsigned)h[6] | ((unsigned)h[7] << 16);
    return u;
}

// ---------------- convert: fp32 -> frag-order bf16 hi/lo planes + enorm -----
__global__ __launch_bounds__(256) void convert_kernel(
    const float* __restrict__ x, const float* __restrict__ emb,
    unsigned char* __restrict__ xh_g, unsigned char* __restrict__ xl_g,
    unsigned char* __restrict__ eh_g, unsigned char* __restrict__ el_g,
    float* __restrict__ enorm, int* __restrict__ counts,
    float* __restrict__ loss_acc, int* __restrict__ nflagF,
    int* __restrict__ nitems, int* __restrict__ nflagP)
{
    __shared__ float part[32][8];
    int b = blockIdx.x;
    bool is_e = (b >= 1024);
    const float* src = is_e ? emb : x;
    unsigned char* hg = is_e ? eh_g : xh_g;
    unsigned char* lg = is_e ? el_g : xl_g;
    int base_row = (is_e ? (b - 1024) : b) * 32;
    int t = threadIdx.x;
    if (b == 1024) {
        for (int i = t; i < Kn; i += 256) counts[i] = 0;
        if (t == 0) { loss_acc[0] = 0.f; nflagF[0] = 0; nitems[0] = 0; nflagP[0] = 0; }
    }
    int rg = t >> 7, ds = (t >> 4) & 7, rl = t & 15;
    int r = base_row + rg * 16 + rl;
    const float4* s4 = (const float4*)(src + (size_t)r * Dq + ds * 32);
    float v[32];
#pragma unroll
    for (int i = 0; i < 8; ++i) {
        float4 f = s4[i];
        v[i * 4 + 0] = f.x; v[i * 4 + 1] = f.y; v[i * 4 + 2] = f.z; v[i * 4 + 3] = f.w;
    }
    unsigned short hh[32], ll[32];
#pragma unroll
    for (int i = 0; i < 32; ++i) {
        hh[i] = f2bf_rne(v[i]);
        ll[i] = f2bf_rne(v[i] - bf2f(hh[i]));
    }
    size_t gb = ((size_t)(r >> 4) * 8 + ds) * 1024 + rl * 16;
#pragma unroll
    for (int qd = 0; qd < 4; ++qd) {
        *(uint4*)(hg + gb + qd * 256) = packbf(hh + qd * 8);
        *(uint4*)(lg + gb + qd * 256) = packbf(ll + qd * 8);
    }
    if (is_e) {
        float ps = 0.f;
#pragma unroll
        for (int i = 0; i < 32; ++i) ps += v[i] * v[i];
        part[rg * 16 + rl][ds] = ps;
        __syncthreads();
        if (t < 32) {
            float s = 0.f;
#pragma unroll
            for (int j = 0; j < 8; ++j) s += part[t][j];
            enorm[base_row + t] = s;
        }
    }
}

// ---------------- argmin: r10 core + top-3 tracking (verified, 131us) -------
__global__ __launch_bounds__(256, 2) void argmin_kernel(
    const unsigned char* __restrict__ xh_g, const unsigned char* __restrict__ xl_g,
    const unsigned char* __restrict__ eh_g, const unsigned char* __restrict__ el_g,
    const float* __restrict__ enorm,
    float* __restrict__ ws_s1, float* __restrict__ ws_s2,
    float* __restrict__ ws_s3, int* __restrict__ ws_ik)
{
    __shared__ __align__(16) unsigned char lds[69632];
    const int tid = threadIdx.x;
    const int lane = tid & 63, wave = tid >> 6;
    const int wq = wave >> 1, wk = wave & 1;
    const int rl = lane & 15, quad = lane >> 4;
    const int b = blockIdx.x;
    const int qb = (b & 7) * 32 + ((b >> 3) >> 1);   // bijective over 512
    const int split = (b >> 3) & 1;
    const int lane16 = lane * 16;

    auto STAGE = [&](int s) {
        const int kt = s >> 3, ch = s & 7;
        unsigned char* buf = lds + (s & 1) * 32768;
        const unsigned char* src = (wave == 0) ? xh_g : (wave == 1) ? xl_g
                                  : (wave == 2) ? eh_g : el_g;
        const int rb = (wave < 2) ? qb * 8 : (split * 64 + kt * 8);
#pragma unroll
        for (int jj = 0; jj < 8; ++jj)
            async_copy16(src + ((size_t)(rb + jj) * 8 + ch) * 1024 + lane16,
                         buf + wave * 8192 + jj * 1024);
    };

    ((float4*)(lds + 65536))[tid] = ((const float4*)(enorm + split * 1024))[tid];
    STAGE(0);
    __syncthreads();

    float s1[16], s2[16], s3[16];
    int i1[16], i2[16];
#pragma unroll
    for (int s = 0; s < 16; ++s) {
        s1[s] = 3.4e38f; s2[s] = 3.4e38f; s3[s] = 3.4e38f; i1[s] = 0; i2[s] = 0;
    }
    f32x4 acc[4][4];

    for (int s = 0; s < 64; ++s) {
        const int kt = s >> 3, ch = s & 7;
        if (ch == 0) {
#pragma unroll
            for (int mf = 0; mf < 4; ++mf)
#pragma unroll
                for (int nf = 0; nf < 4; ++nf)
                    acc[mf][nf] = (f32x4){0.f, 0.f, 0.f, 0.f};
        }
        if (s < 63) STAGE(s + 1);          // in flight across the MFMA cluster

        const unsigned char* buf = lds + (s & 1) * 32768;
        bf16x8 ah[4], al[4], bh[4], bl[4];
#pragma unroll
        for (int mf = 0; mf < 4; ++mf) {
            ah[mf] = *(const bf16x8*)(buf + (wq * 4 + mf) * 1024 + lane16);
            al[mf] = *(const bf16x8*)(buf + 8192 + (wq * 4 + mf) * 1024 + lane16);
        }
#pragma unroll
        for (int nf = 0; nf < 4; ++nf) {
            bh[nf] = *(const bf16x8*)(buf + 16384 + (wk * 4 + nf) * 1024 + lane16);
            bl[nf] = *(const bf16x8*)(buf + 24576 + (wk * 4 + nf) * 1024 + lane16);
        }
#pragma unroll
        for (int mf = 0; mf < 4; ++mf)
#pragma unroll
            for (int nf = 0; nf < 4; ++nf) {
                acc[mf][nf] = __builtin_amdgcn_mfma_f32_16x16x32_bf16(
                    ah[mf], bh[nf], acc[mf][nf], 0, 0, 0);
                acc[mf][nf] = __builtin_amdgcn_mfma_f32_16x16x32_bf16(
                    ah[mf], bl[nf], acc[mf][nf], 0, 0, 0);
                acc[mf][nf] = __builtin_amdgcn_mfma_f32_16x16x32_bf16(
                    al[mf], bh[nf], acc[mf][nf], 0, 0, 0);
            }

        if (ch == 7) {
            // fold scores; codes arrive in ascending order per slot
#pragma unroll
            for (int nf = 0; nf < 4; ++nf) {
                float ee = *(const float*)(lds + 65536 +
                             (kt * 128 + wk * 64 + nf * 16 + rl) * 4);
                int code = kt * 4 + nf;
#pragma unroll
                for (int mf = 0; mf < 4; ++mf)
#pragma unroll
                    for (int r = 0; r < 4; ++r) {
                        int slot = mf * 4 + r;
                        float sc = fmaf(-2.f, acc[mf][nf][r], ee);
                        bool lt1 = sc < s1[slot];
                        bool lt2 = sc < s2[slot];
                        s3[slot] = lt2 ? s2[slot] : fminf(s3[slot], sc);
                        s2[slot] = lt1 ? s1[slot] : (lt2 ? sc : s2[slot]);
                        i2[slot] = lt1 ? i1[slot] : (lt2 ? code : i2[slot]);
                        s1[slot] = lt1 ? sc : s1[slot];
                        i1[slot] = lt1 ? code : i1[slot];
                    }
            }
        }
        __syncthreads();   // drains STAGE(s+1) after the 48-MFMA cluster
    }

    // local codes -> global code ids
    int k1[16], k2[16];
#pragma unroll
    for (int s = 0; s < 16; ++s) {
        k1[s] = split * 1024 + (i1[s] >> 2) * 128 + wk * 64 + (i1[s] & 3) * 16 + rl;
        k2[s] = split * 1024 + (i2[s] >> 2) * 128 + wk * 64 + (i2[s] & 3) * 16 + rl;
    }
    // butterfly merge across the 16 lanes holding the same query rows
#pragma unroll
    for (int m = 1; m <= 8; m <<= 1) {
#pragma unroll
        for (int s = 0; s < 16; ++s) {
            float t1 = __shfl_xor(s1[s], m, 64);
            float t2 = __shfl_xor(s2[s], m, 64);
            float t3 = __shfl_xor(s3[s], m, 64);
            int   j1 = __shfl_xor(k1[s], m, 64);
            int   j2 = __shfl_xor(k2[s], m, 64);
            bool a1 = (t1 < s1[s]) || (t1 == s1[s] && j1 < k1[s]);
            bool a2 = (t1 < s2[s]) || (t1 == s2[s] && j1 < k2[s]);
            s3[s] = a2 ? s2[s] : fminf(s3[s], t1);
            s2[s] = a1 ? s1[s] : (a2 ? t1 : s2[s]);
            k2[s] = a1 ? k1[s] : (a2 ? j1 : k2[s]);
            s1[s] = a1 ? t1 : s1[s];
            k1[s] = a1 ? j1 : k1[s];
            bool b1 = (t2 < s1[s]) || (t2 == s1[s] && j2 < k1[s]);
            bool b2 = (t2 < s2[s]) || (t2 == s2[s] && j2 < k2[s]);
            s3[s] = b2 ? s2[s] : fminf(s3[s], t2);
            s2[s] = b1 ? s1[s] : (b2 ? t2 : s2[s]);
            k2[s] = b1 ? k1[s] : (b2 ? j2 : k2[s]);
            s1[s] = b1 ? t2 : s1[s];
            k1[s] = b1 ? j2 : k1[s];
            s3[s] = fminf(s3[s], t3);
        }
    }
    __syncthreads();
    float* rs1 = (float*)lds;
    float* rs2 = (float*)(lds + 1024);
    float* rs3 = (float*)(lds + 2048);
    int*   rk  = (int*)(lds + 3072);
    if (rl == 0) {
#pragma unroll
        for (int s = 0; s < 16; ++s) {
            int ql = wq * 64 + (s >> 2) * 16 + quad * 4 + (s & 3);
            rs1[ql * 2 + wk] = s1[s];
            rs2[ql * 2 + wk] = s2[s];
            rs3[ql * 2 + wk] = s3[s];
            rk[ql * 2 + wk]  = k1[s] | (k2[s] << 11);
        }
    }
    __syncthreads();
    if (tid < 128) {
        float a1 = rs1[tid * 2], a2 = rs2[tid * 2], a3 = rs3[tid * 2];
        int kk = rk[tid * 2];
        int m1 = kk & 2047, m2 = (kk >> 11) & 2047;
        float t1 = rs1[tid * 2 + 1], t2 = rs2[tid * 2 + 1], t3 = rs3[tid * 2 + 1];
        int kj = rk[tid * 2 + 1];
        int j1 = kj & 2047, j2 = (kj >> 11) & 2047;
        bool c1 = (t1 < a1) || (t1 == a1 && j1 < m1);
        bool c2 = (t1 < a2) || (t1 == a2 && j1 < m2);
        a3 = c2 ? a2 : fminf(a3, t1);
        a2 = c1 ? a1 : (c2 ? t1 : a2);
        m2 = c1 ? m1 : (c2 ? j1 : m2);
        a1 = c1 ? t1 : a1;
        m1 = c1 ? j1 : m1;
        bool d1 = (t2 < a1) || (t2 == a1 && j2 < m1);
        bool d2 = (t2 < a2) || (t2 == a2 && j2 < m2);
        a3 = d2 ? a2 : fminf(a3, t2);
        a2 = d1 ? a1 : (d2 ? t2 : a2);
        m2 = d1 ? m1 : (d2 ? j2 : m2);
        a1 = d1 ? t2 : a1;
        m1 = d1 ? j2 : m1;
        a3 = fminf(a3, t3);
        int q = qb * 128 + tid;
        ws_s1[split * Nq + q] = a1;
        ws_s2[split * Nq + q] = a2;
        ws_s3[split * Nq + q] = a3;
        ws_ik[split * Nq + q] = m1 | (m2 << 11);
    }
}

// ---------------- pick(+hist+zero): merge splits, route, count, zero accum --
// grid 640: blocks 0..127 pick 256 queries each; blocks 128..639 zero accum.
__global__ __launch_bounds__(256) void pick_kernel(
    const float* __restrict__ ws_s1, const float* __restrict__ ws_s2,
    const float* __restrict__ ws_s3, const int* __restrict__ ws_ik,
    int* __restrict__ idx,
    int* __restrict__ nflagF, int* __restrict__ flaglist,
    int* __restrict__ nflagP, int* __restrict__ pairlist,
    int* __restrict__ counts, float* __restrict__ accum)
{
    int b = blockIdx.x;
    if (b >= 128) {
        int zi = (b - 128) * 256 + threadIdx.x;   // 512 blk x 256 thr x 16B = 2MB
        ((float4*)accum)[zi] = (float4){0.f, 0.f, 0.f, 0.f};
        return;
    }
    int q = b * 256 + threadIdx.x;
    float a1 = ws_s1[q], a2 = ws_s2[q], a3 = ws_s3[q];
    int kk = ws_ik[q];
    int m1 = kk & 2047, m2 = (kk >> 11) & 2047;
    float t1 = ws_s1[Nq + q], t2 = ws_s2[Nq + q], t3 = ws_s3[Nq + q];
    int kj = ws_ik[Nq + q];
    int j1 = kj & 2047, j2 = (kj >> 11) & 2047;
    bool c1 = (t1 < a1) || (t1 == a1 && j1 < m1);
    bool c2 = (t1 < a2) || (t1 == a2 && j1 < m2);
    a3 = c2 ? a2 : fminf(a3, t1);
    a2 = c1 ? a1 : (c2 ? t1 : a2);
    m2 = c1 ? m1 : (c2 ? j1 : m2);
    a1 = c1 ? t1 : a1;
    m1 = c1 ? j1 : m1;
    bool d1 = (t2 < a1) || (t2 == a1 && j2 < m1);
    bool d2 = (t2 < a2) || (t2 == a2 && j2 < m2);
    a3 = d2 ? a2 : fminf(a3, t2);
    a2 = d1 ? a1 : (d2 ? t2 : a2);
    m2 = d1 ? m1 : (d2 ? j2 : m2);
    a1 = d1 ? t2 : a1;
    m1 = d1 ? j2 : m1;
    a3 = fminf(a3, t3);

    idx[q] = m1;
    atomicAdd(&counts[m1], 1);          // hist folded in; rescues fix up
    if (a3 - a1 < MARGIN) {
        int p = atomicAdd(nflagF, 1);
        flaglist[p] = q;
    } else if (a2 - a1 < MARGIN) {
        int p = atomicAdd(nflagP, 1);
        pairlist[p] = q | (m2 << 16);
    }
}

// ---------------- rescue (merged): full scans then pair checks --------------
__global__ __launch_bounds__(256) void rescue_kernel(
    const float* __restrict__ x, const float* __restrict__ emb,
    const float* __restrict__ enorm, const int* __restrict__ flaglist,
    const int* __restrict__ nflagF, const int* __restrict__ pairlist,
    const int* __restrict__ nflagP, int* __restrict__ idx,
    int* __restrict__ counts)
{
    __shared__ float xs[256];
    __shared__ float bsc[256];
    __shared__ int bix[256];
    const int t = threadIdx.x;
    // ---- phase 1: exact full scan, one flagged query per block (stride) ----
    int nf = nflagF[0];
    for (int it = blockIdx.x; it < nf; it += gridDim.x) {
        __syncthreads();
        int q = flaglist[it];
        xs[t] = x[(size_t)q * Dq + t];
        __syncthreads();
        float best = 3.4e38f;
        int bk = 0;
        for (int j = 0; j < 8; ++j) {
            int k = j * 256 + t;
            const float4* e4 = (const float4*)(emb + (size_t)k * Dq);
            const float4* x4 = (const float4*)xs;
            float d = 0.f;
#pragma unroll 8
            for (int c = 0; c < 64; ++c) {
                float4 e = e4[c], xv = x4[c];
                d = fmaf(e.x, xv.x, d); d = fmaf(e.y, xv.y, d);
                d = fmaf(e.z, xv.z, d); d = fmaf(e.w, xv.w, d);
            }
            float sc = enorm[k] - 2.f * d;
            if (sc < best || (sc == best && k < bk)) { best = sc; bk = k; }
        }
        bsc[t] = best; bix[t] = bk;
        __syncthreads();
        for (int o = 128; o > 0; o >>= 1) {
            if (t < o) {
                float so = bsc[t + o]; int io = bix[t + o];
                if (so < bsc[t] || (so == bsc[t] && io < bix[t])) {
                    bsc[t] = so; bix[t] = io;
                }
            }
            __syncthreads();
        }
        if (t == 0) {
            int old = idx[q];
            if (bix[0] != old) {
                idx[q] = bix[0];
                atomicSub(&counts[old], 1);
                atomicAdd(&counts[bix[0]], 1);
            }
        }
    }
    // ---- phase 2: exact pair check, one query per thread (stride) ----------
    int np = nflagP[0];
    for (int p = blockIdx.x * 256 + t; p < np; p += gridDim.x * 256) {
        int e = pairlist[p];
        int q = e & 0xFFFF;
        int c2 = e >> 16;
        int c1 = idx[q];
        const float4* x4 = (const float4*)(x + (size_t)q * Dq);
        const float4* e1 = (const float4*)(emb + (size_t)c1 * Dq);
        const float4* e2 = (const float4*)(emb + (size_t)c2 * Dq);
        float d1 = 0.f, d2 = 0.f;
#pragma unroll 8
        for (int c = 0; c < 64; ++c) {
            float4 xv = x4[c];
            float4 ea = e1[c];
            float4 eb = e2[c];
            d1 = fmaf(ea.x, xv.x, d1); d1 = fmaf(ea.y, xv.y, d1);
            d1 = fmaf(ea.z, xv.z, d1); d1 = fmaf(ea.w, xv.w, d1);
            d2 = fmaf(eb.x, xv.x, d2); d2 = fmaf(eb.y, xv.y, d2);
            d2 = fmaf(eb.z, xv.z, d2); d2 = fmaf(eb.w, xv.w, d2);
        }
        float sc1 = enorm[c1] - 2.f * d1;
        float sc2 = enorm[c2] - 2.f * d2;
        if (sc2 < sc1 || (sc2 == sc1 && c2 < c1)) {
            idx[q] = c2;
            atomicSub(&counts[c1], 1);
            atomicAdd(&counts[c2], 1);
        }
    }
}

// ---------------- scan: offsets + smoothed counts + work items --------------
__global__ __launch_bounds__(256) void scan_kernel(
    const int* __restrict__ counts, const float* __restrict__ ema_count,
    int* __restrict__ offs, int* __restrict__ cursor,
    float* __restrict__ cnew, float* __restrict__ out_count,
    int* __restrict__ items, int* __restrict__ nitems)
{
    __shared__ int   si[256];
    __shared__ float sf[256];
    int t = threadIdx.x;
    int c[8], pre[8];
    int run = 0;
    float se = 0.f;
#pragma unroll
    for (int i = 0; i < 8; ++i) {
        c[i] = counts[t * 8 + i];
        pre[i] = run;
        run += c[i];
        se += ema_count[t * 8 + i];
    }
    si[t] = run;
    sf[t] = se;
    __syncthreads();
    for (int off = 1; off < 256; off <<= 1) {
        int v = (t >= off) ? si[t - off] : 0;
        __syncthreads();
        si[t] += v;
        __syncthreads();
    }
    int total_n = si[255];
    int base = si[t] - run;
    for (int off = 128; off > 0; off >>= 1) {
        if (t < off) sf[t] += sf[t + off];
        __syncthreads();
    }
    float total = DECAY * sf[0] + OMD * (float)total_n;
    float denom = total + 2048.0f * EPSC;
#pragma unroll
    for (int i = 0; i < 8; ++i) {
        int k = t * 8 + i;
        int o = base + pre[i];
        offs[k] = o;
        cursor[k] = o;
        float ck = DECAY * ema_count[k] + OMD * (float)c[i];
        float v = (ck + EPSC) / denom * total;
        cnew[k] = v;
        out_count[k] = v;
        if (c[i] > 0) {
            int nit = (c[i] + 31) >> 5;
            int ib = atomicAdd(nitems, nit);
            for (int j = 0; j < nit; ++j)
                items[ib + j] = (k << 17) | (o + j * 32);
        }
    }
}

// ---------------- fill: bucket queries by code ------------------------------
__global__ __launch_bounds__(256) void fill_kernel(const int* __restrict__ idx,
                                                   int* __restrict__ cursor,
                                                   int* __restrict__ sorted) {
    int n = blockIdx.x * 256 + threadIdx.x;
    int v = idx[n];
    int pos = atomicAdd(&cursor[v], 1);
    sorted[pos] = n;
}

// ---------------- weight_partial: <=32 rows per item, atomic accum ----------
__global__ __launch_bounds__(256) void weight_partial_kernel(
    const float* __restrict__ x, const int* __restrict__ sorted,
    const int* __restrict__ items, const int* __restrict__ nitems,
    const int* __restrict__ counts, const int* __restrict__ offs,
    float* __restrict__ accum)
{
    if ((int)blockIdx.x >= nitems[0]) return;
    int it = items[blockIdx.x];
    int k = it >> 17;
    int start = it & 0x1FFFF;
    int end = min(start + 32, offs[k] + counts[k]);
    int t = threadIdx.x;
    float acc = 0.f;
    int j = start;
    for (; j + 4 <= end; j += 4) {
        int n0 = sorted[j + 0], n1 = sorted[j + 1];
        int n2 = sorted[j + 2], n3 = sorted[j + 3];
        float v0 = x[(size_t)n0 * Dq + t];
        float v1 = x[(size_t)n1 * Dq + t];
        float v2 = x[(size_t)n2 * Dq + t];
        float v3 = x[(size_t)n3 * Dq + t];
        acc += v0 + v1 + v2 + v3;
    }
    for (; j < end; ++j) {
        int n = sorted[j];
        acc += x[(size_t)n * Dq + t];
    }
    atomicAdd(&accum[(size_t)k * Dq + t], acc);
}

// ---------------- wf_fin: weight_final (blocks<512) + finalize (>=512) ------
__global__ __launch_bounds__(256) void wf_fin_kernel(
    const float* __restrict__ accum, const float* __restrict__ ema_weight,
    const float* __restrict__ cnew,
    float* __restrict__ out_embed, float* __restrict__ out_weight,
    const int* __restrict__ idx, const float* __restrict__ x,
    const float* __restrict__ emb, float* __restrict__ idx_f_out,
    float* __restrict__ zq_out, float* __restrict__ loss_acc)
{
    __shared__ int sidx[64];
    __shared__ float lpart[4];
    const int tid = threadIdx.x;
    const int b = blockIdx.x;
    if (b < 512) {
        // ---- weight_final: EMA + divide --------------------------------
        int gi = b * 256 + tid;                // float4 index
        int k = gi >> 6;                       // 64 float4 per row
        float4 a = ((const float4*)accum)[gi];
        float4 ew = ((const float4*)ema_weight)[gi];
        float inv = 1.f / cnew[k];
        float4 w;
        w.x = DECAY * ew.x + OMD * a.x;
        w.y = DECAY * ew.y + OMD * a.y;
        w.z = DECAY * ew.z + OMD * a.z;
        w.w = DECAY * ew.w + OMD * a.w;
        ((float4*)out_weight)[gi] = w;
        float4 e;
        e.x = w.x * inv; e.y = w.y * inv; e.z = w.z * inv; e.w = w.w * inv;
        ((float4*)out_embed)[gi] = e;
        return;
    }
    // ---- finalize: idx_f + gather z_q + loss -------------------------------
    const int q0 = (b - 512) * 64;
    if (tid < 64) {
        int bi = idx[q0 + tid];
        idx_f_out[q0 + tid] = (float)bi;
        sidx[tid] = bi;
    }
    __syncthreads();
    int gq = tid >> 2, part = tid & 3;
    int bk = sidx[gq];
    const float4* ev = (const float4*)&emb[(size_t)bk * Dq + part * 64];
    const float4* xv = (const float4*)&x[(size_t)(q0 + gq) * Dq + part * 64];
    float4* ov = (float4*)&zq_out[(size_t)(q0 + gq) * Dq + part * 64];
    float lacc = 0.f;
#pragma unroll 4
    for (int t2 = 0; t2 < 16; ++t2) {
        float4 e4 = ev[t2];
        float4 x4 = xv[t2];
        ov[t2] = e4;
        float d0 = x4.x - e4.x, d1 = x4.y - e4.y;
        float d2 = x4.z - e4.z, d3 = x4.w - e4.w;
        lacc += d0 * d0 + d1 * d1 + d2 * d2 + d3 * d3;
    }
#pragma unroll
    for (int o = 32; o > 0; o >>= 1) lacc += __shfl_down(lacc, o, 64);
    if ((tid & 63) == 0) lpart[tid >> 6] = lacc;
    __syncthreads();
    if (tid == 0)
        atomicAdd(loss_acc, lpart[0] + lpart[1] + lpart[2] + lpart[3]);
}

// ---------------- loss_final ------------------------------------------------
__global__ void loss_final_kernel(const float* __restrict__ loss_acc,
                                  float* __restrict__ out_cb,
                                  float* __restrict__ out_cm) {
    float v = loss_acc[0] / (float)((size_t)Nq * Dq);
    out_cb[0] = v;
    out_cm[0] = v;
}

// ---------------------------------------------------------------------------
extern "C" void kernel_launch(void* const* d_in, const int* in_sizes, int n_in,
                              void* d_out, int out_size, void* d_ws, size_t ws_size,
                              hipStream_t stream) {
    const float* z_e        = (const float*)d_in[0];
    const float* emb        = (const float*)d_in[1];
    const float* ema_count  = (const float*)d_in[2];
    const float* ema_weight = (const float*)d_in[3];

    float* out_zq     = (float*)d_out;
    float* out_idx    = out_zq + (size_t)Nq * Dq;            // 8388608
    float* out_cb     = out_idx + Nq;
    float* out_cm     = out_cb + 1;
    float* out_embed  = out_cm + 1;                           // 8421378
    float* out_count  = out_embed + (size_t)Kn * Dq;
    float* out_weight = out_count + Kn;

    // scratch planes + accum live in d_out regions written later:
    unsigned char* xh_g = (unsigned char*)d_out;              // 16 MB (z_q area)
    unsigned char* xl_g = xh_g + 16777216;                    // 16 MB
    size_t eh_off = (((size_t)8421378 * 4) + 15) & ~(size_t)15;
    unsigned char* eh_g = (unsigned char*)d_out + eh_off;     // 1 MB (embed area)
    unsigned char* el_g = eh_g + 1048576;                     // 1 MB
    float* accum = (float*)d_out;                             // 2 MB, zeroed in pick

    char* ws = (char*)d_ws;
    float* enorm    = (float*)(ws + 0);
    int*   counts   = (int*)(ws + 8192);
    int*   offs     = (int*)(ws + 16384);
    int*   cursor   = (int*)(ws + 24576);
    float* cnew     = (float*)(ws + 32768);
    float* loss_acc = (float*)(ws + 40960);
    int*   nflagF   = (int*)(ws + 40964);
    int*   nitems   = (int*)(ws + 40968);
    int*   nflagP   = (int*)(ws + 40972);
    int*   idx      = (int*)(ws + 49152);       // 32768 i
    int*   sorted   = (int*)(ws + 180224);      // 32768 i
    int*   flaglist = (int*)(ws + 311296);      // 32768 i
    float* ws_s1    = (float*)(ws + 442368);    // 2*32768 f
    float* ws_s2    = (float*)(ws + 704512);    // 2*32768 f
    float* ws_s3    = (float*)(ws + 966656);    // 2*32768 f
    int*   ws_ik    = (int*)(ws + 1228800);     // 2*32768 i
    int*   pairlist = (int*)(ws + 1490944);     // 32768 i
    int*   items    = (int*)(ws + 1622016);     // 3072 i

    convert_kernel<<<1088, 256, 0, stream>>>(z_e, emb, xh_g, xl_g, eh_g, el_g,
                                             enorm, counts, loss_acc, nflagF,
                                             nitems, nflagP);
    argmin_kernel<<<512, 256, 0, stream>>>(xh_g, xl_g, eh_g, el_g, enorm,
                                           ws_s1, ws_s2, ws_s3, ws_ik);
    pick_kernel<<<640, 256, 0, stream>>>(ws_s1, ws_s2, ws_s3, ws_ik, idx,
                                         nflagF, flaglist, nflagP, pairlist,
                                         counts, accum);
    rescue_kernel<<<1024, 256, 0, stream>>>(z_e, emb, enorm, flaglist, nflagF,
                                            pairlist, nflagP, idx, counts);
    scan_kernel<<<1, 256, 0, stream>>>(counts, ema_count, offs, cursor, cnew,
                                       out_count, items, nitems);
    fill_kernel<<<Nq / 256, 256, 0, stream>>>(idx, cursor, sorted);
    weight_partial_kernel<<<MAXITEMS, 256, 0, stream>>>(z_e, sorted, items, nitems,
                                                        counts, offs, accum);
    wf_fin_kernel<<<1024, 256, 0, stream>>>(accum, ema_weight, cnew,
                                            out_embed, out_weight,
                                            idx, z_e, emb, out_idx,
                                            out_zq, loss_acc);
    loss_final_kernel<<<1, 1, 0, stream>>>(loss_acc, out_cb, out_cm);
}